// Round 6
// baseline (15.978 us; speedup 1.0000x reference)
//
#include <hip/hip_runtime.h>

// SurfEval: NURBS surface evaluation (B=4, 1024x1024 grid, 4x4 basis window).
// R5: barrier-free wave-private structure + packed-f32 math.
//  - Grid 2048 = (u, half); block 256 = 4 waves; wave w owns batch b=w and
//    v-half `half`. Each wave computes its own tu[w][128] in LDS (2 entries
//    per lane, full-wave stage 1) and reads ONLY its own region -> no
//    __syncthreads anywhere (same-wave ds ordering via lgkmcnt).
//  - All math on clang ext_vector float4: -ffp-contract=fast + VOP3P emits
//    v_pk_fma_f32, halving FMA issue slots vs scalar fma4 (R0-R4).
//  - v = half*512 + k*64 + lane: consecutive lanes -> consecutive v, LDS
//    reads are ~8-distinct-entry broadcasts, conflict-free (proven fastest).
//  - NT dwordx3 stores, v_rcp_f32 divide (absmax 7.8e-3 << 5.9e-2 thr).

#define OUT_U 1024
#define OUT_V 1024
#define MCTRL 128
#define NCTRL 128

typedef float f4 __attribute__((ext_vector_type(4)));
typedef float vfloat3 __attribute__((ext_vector_type(3), aligned(4)));

__global__ __launch_bounds__(256) void surf_eval_kernel(
    const f4*  __restrict__ ctrl,   // (B,M,N) as float4
    const f4*  __restrict__ Nu,     // (OUT_U)
    const f4*  __restrict__ Nv,     // (OUT_V)
    const int* __restrict__ uspan,  // (OUT_U)
    const int* __restrict__ vspan,  // (OUT_V)
    float*     __restrict__ out)    // (B,OUT_U,OUT_V,3)
{
    __shared__ f4 tu[4][NCTRL];     // per-wave private buffers, 8KB

    const int tid  = threadIdx.x;
    const int w    = tid >> 6;      // wave id == batch index
    const int lane = tid & 63;
    const int u    = blockIdx.x >> 1;
    const int half = blockIdx.x & 1;

    const int us = uspan[u];        // block-uniform -> scalar load
    const f4  nu = Nu[u];

    // Stage 1 (per wave, its own batch): tu[j] = sum_l nu[l]*ctrl[w,us-3+l,j]
    const f4* win = ctrl + ((size_t)(w * MCTRL + (us - 3)) * NCTRL);
#pragma unroll
    for (int h = 0; h < 2; ++h) {
        const int j = lane + h * 64;
        f4 acc = nu.x * win[j];
        acc += nu.y * win[NCTRL + j];
        acc += nu.z * win[2 * NCTRL + j];
        acc += nu.w * win[3 * NCTRL + j];
        tu[w][j] = acc;
    }
    // No barrier: this wave's ds_reads below are ordered after its ds_writes
    // by the compiler's lgkmcnt tracking; no cross-wave LDS sharing.

    // Stage 2: 8 iterations of 64 consecutive v per wave.
    const size_t outrow = ((size_t)w * OUT_U + (size_t)u) * OUT_V;
    const int    vbase  = (half << 9) + lane;
#pragma unroll 4
    for (int k = 0; k < 8; ++k) {
        const int v  = vbase + (k << 6);
        const int vs = vspan[v];    // in [3,127]
        const f4  nv = Nv[v];

        const f4 t0 = tu[w][vs - 3];
        const f4 t1 = tu[w][vs - 2];
        const f4 t2 = tu[w][vs - 1];
        const f4 t3 = tu[w][vs];

        f4 acc = nv.x * t0;
        acc += nv.y * t1;
        acc += nv.z * t2;
        acc += nv.w * t3;

        const float inv = __builtin_amdgcn_rcpf(acc.w);
        vfloat3 res;
        res.x = acc.x * inv;
        res.y = acc.y * inv;
        res.z = acc.z * inv;
        __builtin_nontemporal_store(res, (vfloat3*)(out + (outrow + (size_t)v) * 3));
    }
}

extern "C" void kernel_launch(void* const* d_in, const int* in_sizes, int n_in,
                              void* d_out, int out_size, void* d_ws, size_t ws_size,
                              hipStream_t stream) {
    const f4*  ctrl  = (const f4*)d_in[0];
    const f4*  Nu    = (const f4*)d_in[1];
    const f4*  Nv    = (const f4*)d_in[2];
    const int* uspan = (const int*)d_in[3];
    const int* vspan = (const int*)d_in[4];
    float*     out   = (float*)d_out;

    const int nblocks = OUT_U * 2;  // (u, half): 2048 blocks, 8/CU, 32 waves/CU
    surf_eval_kernel<<<nblocks, 256, 0, stream>>>(ctrl, Nu, Nv, uspan, vspan, out);
}